// Round 1
// baseline (1125.044 us; speedup 1.0000x reference)
//
#include <hip/hip_runtime.h>
#include <hip/hip_bf16.h>

#define NN 50000     // nodes
#define NE 500000    // edges
#define DD 128       // latent size

struct MlpPtrs { const float* W1; const float* b1; const float* W2; const float* b2; int dout; int obase; };
struct MlpArgs { MlpPtrs m[4]; };

// ---------------------------------------------------------------------------
// Kernel 1: 4 fused MLPs per edge + vector combination.
//   h = relu(x @ W1 + b1); coeff = h @ W2 + b2
//   fij/aij/dxij = sum_i coeff_i * vector_i ; lambda = fs output
// Writes fij -> out[0], aij -> out[E*3] (tau slot, temp), dxij -> out[2*E*3],
// lambda -> ws.
// Tiling: 32 edges/block, 256 threads. 8 groups of 32 lanes; group g owns
// edges 4g..4g+3; lane within group owns 4 hidden columns. acc[4 edges][4 j].
// ---------------------------------------------------------------------------
__global__ __launch_bounds__(256) void mlp_kernel(
    const float* __restrict__ latent,
    const float* __restrict__ va, const float* __restrict__ vb, const float* __restrict__ vc,
    float* __restrict__ out, float* __restrict__ lam_ws, MlpArgs args)
{
    __shared__ float Xs[32][DD];   // 16 KB
    __shared__ float Ws[64][DD];   // 32 KB (half of one W1 panel)
    __shared__ float Cf[32][12];   // per-edge coeffs: [0..2]=f [3..5]=a [6]=lam [7..9]=dx

    const int t  = threadIdx.x;
    const int e0 = blockIdx.x * 32;

    // stage X tile (coalesced float4)
    {
        const float4* src = (const float4*)(latent + (size_t)e0 * DD);
        float4* dst = (float4*)&Xs[0][0];
        #pragma unroll
        for (int i = 0; i < 4; ++i) dst[t + i * 256] = src[t + i * 256];
    }

    const int lane32 = t & 31;
    const int eb = (t >> 5) * 4;   // edge base within tile
    const int jb = lane32 * 4;     // hidden column base

    for (int m = 0; m < 4; ++m) {  // keep rolled: code size
        const MlpPtrs P = args.m[m];
        float acc[4][4];
        #pragma unroll
        for (int jj = 0; jj < 4; ++jj) {
            const float bv = P.b1[jb + jj];
            acc[0][jj] = bv; acc[1][jj] = bv; acc[2][jj] = bv; acc[3][jj] = bv;
        }

        for (int h = 0; h < 2; ++h) {           // W1 in two 64-row halves
            __syncthreads();                    // protect Ws (and Xs on first pass)
            const float4* wsrc = (const float4*)(P.W1 + (size_t)h * 64 * DD);
            float4* wdst = (float4*)&Ws[0][0];
            #pragma unroll
            for (int i = 0; i < 8; ++i) wdst[t + i * 256] = wsrc[t + i * 256];
            __syncthreads();

            #pragma unroll 4
            for (int k4 = 0; k4 < 16; ++k4) {
                float4 xa[4], wq[4];
                #pragma unroll
                for (int i = 0; i < 4; ++i) xa[i] = *(const float4*)&Xs[eb + i][h * 64 + k4 * 4];
                #pragma unroll
                for (int kk = 0; kk < 4; ++kk) wq[kk] = *(const float4*)&Ws[k4 * 4 + kk][jb];
                float xv[4][4], wv[4][4];
                #pragma unroll
                for (int i = 0; i < 4; ++i) {
                    xv[i][0] = xa[i].x; xv[i][1] = xa[i].y; xv[i][2] = xa[i].z; xv[i][3] = xa[i].w;
                    wv[i][0] = wq[i].x; wv[i][1] = wq[i].y; wv[i][2] = wq[i].z; wv[i][3] = wq[i].w;
                }
                #pragma unroll
                for (int i = 0; i < 4; ++i)
                    #pragma unroll
                    for (int kk = 0; kk < 4; ++kk)
                        #pragma unroll
                        for (int jj = 0; jj < 4; ++jj)
                            acc[i][jj] = fmaf(xv[i][kk], wv[kk][jj], acc[i][jj]);
            }
        }

        // relu
        #pragma unroll
        for (int i = 0; i < 4; ++i)
            #pragma unroll
            for (int jj = 0; jj < 4; ++jj)
                acc[i][jj] = fmaxf(acc[i][jj], 0.0f);

        // layer 2: out[e][o] = sum_j h[e][j] * W2[j][o] + b2[o]
        for (int o = 0; o < P.dout; ++o) {
            float w2v[4];
            #pragma unroll
            for (int jj = 0; jj < 4; ++jj) w2v[jj] = P.W2[(jb + jj) * P.dout + o];
            #pragma unroll
            for (int i = 0; i < 4; ++i) {
                float p = acc[i][0] * w2v[0] + acc[i][1] * w2v[1] +
                          acc[i][2] * w2v[2] + acc[i][3] * w2v[3];
                // butterfly within 32-lane half-waves
                p += __shfl_xor(p, 16);
                p += __shfl_xor(p, 8);
                p += __shfl_xor(p, 4);
                p += __shfl_xor(p, 2);
                p += __shfl_xor(p, 1);
                if (lane32 == 0) Cf[eb + i][P.obase + o] = p + P.b2[o];
            }
        }
    }

    __syncthreads();

    // epilogue: combine with vectors, write global
    if (t < 32) {
        const int e = e0 + t;
        float c[10];
        #pragma unroll
        for (int q = 0; q < 10; ++q) c[q] = Cf[t][q];
        const float ax = va[(size_t)e*3+0], ay = va[(size_t)e*3+1], az = va[(size_t)e*3+2];
        const float bx = vb[(size_t)e*3+0], by = vb[(size_t)e*3+1], bz = vb[(size_t)e*3+2];
        const float cx = vc[(size_t)e*3+0], cy = vc[(size_t)e*3+1], cz = vc[(size_t)e*3+2];

        const size_t o0 = (size_t)e * 3;
        const size_t o1 = (size_t)NE * 3 + o0;
        const size_t o2 = (size_t)2 * NE * 3 + o0;
        out[o0+0] = c[0]*ax + c[1]*bx + c[2]*cx;
        out[o0+1] = c[0]*ay + c[1]*by + c[2]*cy;
        out[o0+2] = c[0]*az + c[1]*bz + c[2]*cz;
        out[o1+0] = c[3]*ax + c[4]*bx + c[5]*cx;
        out[o1+1] = c[3]*ay + c[4]*by + c[5]*cy;
        out[o1+2] = c[3]*az + c[4]*bz + c[5]*cz;
        out[o2+0] = c[7]*ax + c[8]*bx + c[9]*cx;
        out[o2+1] = c[7]*ay + c[8]*by + c[9]*cy;
        out[o2+2] = c[7]*az + c[8]*bz + c[9]*cz;
        lam_ws[e] = c[6];
    }
}

// ---------------------------------------------------------------------------
__global__ void zero_kernel(float* __restrict__ p, int n)
{
    int i = blockIdx.x * blockDim.x + threadIdx.x;
    if (i < n) p[i] = 0.0f;
}

// segment sums for all three tensors + count, over masked edges
__global__ void seg_sum_kernel(const int* __restrict__ idx, const int* __restrict__ edge_attr,
                               const int* __restrict__ node_type, const float* __restrict__ out,
                               float* __restrict__ sums, float* __restrict__ cnt)
{
    int e = blockIdx.x * blockDim.x + threadIdx.x;
    if (e >= NE) return;
    if (edge_attr[e] != -1) return;                 // virtual edges only
    const int n = idx[e];
    if (node_type[2 * n + 1] != -1) return;         // global nodes only
    atomicAdd(&cnt[n], 1.0f);
    #pragma unroll
    for (int tns = 0; tns < 3; ++tns)
        #pragma unroll
        for (int c2 = 0; c2 < 3; ++c2)
            atomicAdd(&sums[(size_t)tns * 3 * NN + (size_t)n * 3 + c2],
                      out[(size_t)tns * NE * 3 + (size_t)e * 3 + c2]);
}

__global__ void apply_mean_kernel(const int* __restrict__ idx, const int* __restrict__ edge_attr,
                                  const int* __restrict__ node_type, float* __restrict__ out,
                                  const float* __restrict__ sums, const float* __restrict__ cnt)
{
    int e = blockIdx.x * blockDim.x + threadIdx.x;
    if (e >= NE) return;
    if (edge_attr[e] != -1) return;
    const int n = idx[e];
    if (node_type[2 * n + 1] != -1) return;
    const float ic = 1.0f / fmaxf(cnt[n], 1.0f);
    #pragma unroll
    for (int tns = 0; tns < 3; ++tns)
        #pragma unroll
        for (int c2 = 0; c2 < 3; ++c2)
            out[(size_t)tns * NE * 3 + (size_t)e * 3 + c2] -=
                sums[(size_t)tns * 3 * NN + (size_t)n * 3 + c2] * ic;
}

// tau = aij - cross(lever, fij*lambda); lever = rp - (ws*sp + wr*rp)/(ws+wr)
__global__ void finalize_kernel(const int* __restrict__ senders, const int* __restrict__ receivers,
                                const float* __restrict__ sp, const float* __restrict__ rp,
                                const float* __restrict__ wn, const float* __restrict__ lam,
                                float* __restrict__ out)
{
    int e = blockIdx.x * blockDim.x + threadIdx.x;
    if (e >= NE) return;
    const int s = senders[e], r = receivers[e];
    const float wsv = wn[s], wrv = wn[r];
    const float inv = 1.0f / (wsv + wrv);
    const size_t b = (size_t)e * 3;
    const float spx = sp[b+0], spy = sp[b+1], spz = sp[b+2];
    const float rpx = rp[b+0], rpy = rp[b+1], rpz = rp[b+2];
    const float lx = rpx - (wsv * spx + wrv * rpx) * inv;
    const float ly = rpy - (wsv * spy + wrv * rpy) * inv;
    const float lz = rpz - (wsv * spz + wrv * rpz) * inv;
    const float lv = lam[e];
    const float gx = out[b+0] * lv, gy = out[b+1] * lv, gz = out[b+2] * lv;
    const size_t tb = (size_t)NE * 3 + b;
    const float tx = out[tb+0] - (ly * gz - lz * gy);
    const float ty = out[tb+1] - (lz * gx - lx * gz);
    const float tz = out[tb+2] - (lx * gy - ly * gx);
    out[tb+0] = tx; out[tb+1] = ty; out[tb+2] = tz;
}

// ---------------------------------------------------------------------------
extern "C" void kernel_launch(void* const* d_in, const int* in_sizes, int n_in,
                              void* d_out, int out_size, void* d_ws, size_t ws_size,
                              hipStream_t stream)
{
    (void)in_sizes; (void)n_in; (void)out_size; (void)ws_size;

    const int* edge_index    = (const int*)d_in[0];
    const int* edge_attr     = (const int*)d_in[1];
    const int* node_type     = (const int*)d_in[2];
    const float* senders_pos = (const float*)d_in[3];
    const float* recv_pos    = (const float*)d_in[4];
    const float* vector_a    = (const float*)d_in[5];
    const float* vector_b    = (const float*)d_in[6];
    const float* vector_c    = (const float*)d_in[7];
    const float* latent      = (const float*)d_in[8];
    const float* w_nodes     = (const float*)d_in[9];

    MlpArgs ma;
    const int douts[4] = {3, 3, 1, 3};
    const int obase[4] = {0, 3, 6, 7};
    for (int i = 0; i < 4; ++i) {
        ma.m[i].W1 = (const float*)d_in[10 + i * 4 + 0];
        ma.m[i].b1 = (const float*)d_in[10 + i * 4 + 1];
        ma.m[i].W2 = (const float*)d_in[10 + i * 4 + 2];
        ma.m[i].b2 = (const float*)d_in[10 + i * 4 + 3];
        ma.m[i].dout = douts[i];
        ma.m[i].obase = obase[i];
    }

    float* out = (float*)d_out;
    // workspace layout (floats): [lambda NE][sIn 9N][cIn N][sOut 9N][cOut N] = 6 MB
    float* lam    = (float*)d_ws;
    float* segbuf = lam + NE;
    float* sIn    = segbuf;
    float* cIn    = sIn + 9 * NN;
    float* sOut   = cIn + NN;
    float* cOut   = sOut + 9 * NN;

    const int* senders   = edge_index;
    const int* receivers = edge_index + NE;

    hipLaunchKernelGGL(zero_kernel, dim3((20 * NN + 255) / 256), dim3(256), 0, stream,
                       segbuf, 20 * NN);
    hipLaunchKernelGGL(mlp_kernel, dim3(NE / 32), dim3(256), 0, stream,
                       latent, vector_a, vector_b, vector_c, out, lam, ma);
    dim3 gE((NE + 255) / 256);
    // mask_in: virtual & global[receivers]
    hipLaunchKernelGGL(seg_sum_kernel,    gE, dim3(256), 0, stream, receivers, edge_attr, node_type, out, sIn, cIn);
    hipLaunchKernelGGL(apply_mean_kernel, gE, dim3(256), 0, stream, receivers, edge_attr, node_type, out, sIn, cIn);
    // mask_out: virtual & global[senders] (uses updated tensors)
    hipLaunchKernelGGL(seg_sum_kernel,    gE, dim3(256), 0, stream, senders, edge_attr, node_type, out, sOut, cOut);
    hipLaunchKernelGGL(apply_mean_kernel, gE, dim3(256), 0, stream, senders, edge_attr, node_type, out, sOut, cOut);
    hipLaunchKernelGGL(finalize_kernel,   gE, dim3(256), 0, stream, senders, receivers, senders_pos, recv_pos, w_nodes, lam, out);
}

// Round 3
// 285.393 us; speedup vs baseline: 3.9421x; 3.9421x over previous
//
#include <hip/hip_runtime.h>
#include <hip/hip_bf16.h>

#define NN 50000     // nodes
#define NE 500000    // edges
#define DD 128       // latent size

typedef float  f32x4 __attribute__((ext_vector_type(4)));
typedef short  s16x8 __attribute__((ext_vector_type(8)));

struct MlpPtrs { const float* W1; const float* b1; const float* W2; const float* b2; int dout; int obase; };
struct MlpArgs { MlpPtrs m[4]; };

__device__ __forceinline__ unsigned short f2bf(float f) {
    unsigned int u = __builtin_bit_cast(unsigned int, f);
    u += 0x7fffu + ((u >> 16) & 1u);           // RNE
    return (unsigned short)(u >> 16);
}

// ---------------------------------------------------------------------------
// Prep: W1T bf16 [m][j][k]  (transposed so B-fragments read 8 contiguous k)
// ---------------------------------------------------------------------------
__global__ void prep_w1t_kernel(const float* __restrict__ W1a, const float* __restrict__ W1b,
                                const float* __restrict__ W1c, const float* __restrict__ W1d,
                                unsigned short* __restrict__ w1t)
{
    int idx = blockIdx.x * blockDim.x + threadIdx.x;   // 4*128*128
    if (idx >= 4 * DD * DD) return;
    int m = idx >> 14, r = idx & 16383;
    int j = r >> 7, k = r & 127;
    const float* W1 = (m == 0) ? W1a : (m == 1) ? W1b : (m == 2) ? W1c : W1d;
    w1t[idx] = f2bf(W1[k * DD + j]);
}

// ---------------------------------------------------------------------------
// Fused 4-MLP kernel with bf16 MFMA layer-1.
// 4 waves/block, 32 edges/wave (2 M-fragments), K=128, N=128 per MLP.
// A frags in registers; W1T panel in LDS (rows padded to 136 shorts -> 2-way
// bank aliasing only); layer-2 via shfl reduce; epilogue combines vectors.
// ---------------------------------------------------------------------------
__global__ __launch_bounds__(256) void mlp_mfma_kernel(
    const float* __restrict__ latent, const unsigned short* __restrict__ w1t,
    const float* __restrict__ va, const float* __restrict__ vb, const float* __restrict__ vc,
    float* __restrict__ out, float* __restrict__ lam_ws, MlpArgs args)
{
    __shared__ unsigned short Ws[DD * 136];   // 34.8 KB
    __shared__ float W2s[DD * 3];             // 1.5 KB
    __shared__ float Cf[4][32][10];           // 5 KB

    const int t = threadIdx.x;
    const int wave = t >> 6, l = t & 63;
    const int lg = l >> 4, lr = l & 15;       // 16-lane group id / lane-in-group
    const int e0 = blockIdx.x * 128 + wave * 32;

    // ---- A fragments: a[mf][kc], edge row = lr (+16*mf), k = lg*8 + kc*32 + b
    s16x8 a[2][4];
    #pragma unroll
    for (int mf = 0; mf < 2; ++mf) {
        int e = e0 + mf * 16 + lr; if (e >= NE) e = NE - 1;
        const float* src = latent + (size_t)e * DD + lg * 8;
        #pragma unroll
        for (int kc = 0; kc < 4; ++kc) {
            float4 x0 = *(const float4*)(src + kc * 32);
            float4 x1 = *(const float4*)(src + kc * 32 + 4);
            s16x8 v;
            v[0] = (short)f2bf(x0.x); v[1] = (short)f2bf(x0.y);
            v[2] = (short)f2bf(x0.z); v[3] = (short)f2bf(x0.w);
            v[4] = (short)f2bf(x1.x); v[5] = (short)f2bf(x1.y);
            v[6] = (short)f2bf(x1.z); v[7] = (short)f2bf(x1.w);
            a[mf][kc] = v;
        }
    }

    for (int m = 0; m < 4; ++m) {
        const MlpPtrs P = args.m[m];
        __syncthreads();                       // everyone done with previous Ws
        // stage W1T panel (32 KB = 2048 uint4) — coalesced dwordx4, padded ds_write
        {
            const uint4* src = (const uint4*)(w1t + m * DD * DD);
            #pragma unroll
            for (int i = 0; i < 8; ++i) {                  // 8*256 = 2048 units
                int idx16 = t + i * 256;                   // 16-byte units
                uint4 vv = src[idx16];
                int j = idx16 >> 4, k = (idx16 & 15) * 8;  // 16 units per 128-short row
                *(uint4*)&Ws[j * 136 + k] = vv;
            }
        }
        for (int i = t; i < DD * P.dout; i += 256) W2s[i] = P.W2[i];
        __syncthreads();

        // ---- layer 1: MFMA
        f32x4 acc[2][8];
        #pragma unroll
        for (int mf = 0; mf < 2; ++mf)
            #pragma unroll
            for (int nf = 0; nf < 8; ++nf) {
                f32x4 z = {0.f, 0.f, 0.f, 0.f};
                acc[mf][nf] = z;
            }
        #pragma unroll
        for (int nf = 0; nf < 8; ++nf) {
            #pragma unroll
            for (int kc = 0; kc < 4; ++kc) {
                s16x8 b = *(const s16x8*)&Ws[(lr + 16 * nf) * 136 + lg * 8 + kc * 32];
                acc[0][nf] = __builtin_amdgcn_mfma_f32_16x16x32_bf16(a[0][kc], b, acc[0][nf], 0, 0, 0);
                acc[1][nf] = __builtin_amdgcn_mfma_f32_16x16x32_bf16(a[1][kc], b, acc[1][nf], 0, 0, 0);
            }
        }
        // bias + relu  (C layout: col j = lr + 16*nf, row = mf*16 + lg*4 + r)
        #pragma unroll
        for (int nf = 0; nf < 8; ++nf) {
            float bv = P.b1[16 * nf + lr];
            #pragma unroll
            for (int mf = 0; mf < 2; ++mf)
                #pragma unroll
                for (int r = 0; r < 4; ++r)
                    acc[mf][nf][r] = fmaxf(acc[mf][nf][r] + bv, 0.f);
        }
        // ---- layer 2: coeff[e][o] = sum_j h[e][j] W2[j][o] + b2[o]
        for (int o = 0; o < P.dout; ++o) {
            float w2v[8];
            #pragma unroll
            for (int nf = 0; nf < 8; ++nf) w2v[nf] = W2s[(16 * nf + lr) * P.dout + o];
            float p[2][4];
            #pragma unroll
            for (int mf = 0; mf < 2; ++mf)
                #pragma unroll
                for (int r = 0; r < 4; ++r) {
                    float s = 0.f;
                    #pragma unroll
                    for (int nf = 0; nf < 8; ++nf) s = fmaf(acc[mf][nf][r], w2v[nf], s);
                    s += __shfl_xor(s, 8);
                    s += __shfl_xor(s, 4);
                    s += __shfl_xor(s, 2);
                    s += __shfl_xor(s, 1);
                    p[mf][r] = s;
                }
            if (lr == 0) {
                float b2v = P.b2[o];
                #pragma unroll
                for (int mf = 0; mf < 2; ++mf)
                    #pragma unroll
                    for (int r = 0; r < 4; ++r)
                        Cf[wave][mf * 16 + lg * 4 + r][P.obase + o] = p[mf][r] + b2v;
            }
        }
    }
    __syncthreads();

    // ---- epilogue: combine coeffs with vectors
    if (l < 32) {
        const int e = e0 + l;
        if (e < NE) {
            float c[10];
            #pragma unroll
            for (int q = 0; q < 10; ++q) c[q] = Cf[wave][l][q];
            const float ax = va[(size_t)e*3+0], ay = va[(size_t)e*3+1], az = va[(size_t)e*3+2];
            const float bx = vb[(size_t)e*3+0], by = vb[(size_t)e*3+1], bz = vb[(size_t)e*3+2];
            const float cx = vc[(size_t)e*3+0], cy = vc[(size_t)e*3+1], cz = vc[(size_t)e*3+2];
            const size_t o0 = (size_t)e * 3;
            const size_t o1 = (size_t)NE * 3 + o0;
            const size_t o2 = (size_t)2 * NE * 3 + o0;
            out[o0+0] = c[0]*ax + c[1]*bx + c[2]*cx;
            out[o0+1] = c[0]*ay + c[1]*by + c[2]*cy;
            out[o0+2] = c[0]*az + c[1]*bz + c[2]*cz;
            out[o1+0] = c[3]*ax + c[4]*bx + c[5]*cx;
            out[o1+1] = c[3]*ay + c[4]*by + c[5]*cy;
            out[o1+2] = c[3]*az + c[4]*bz + c[5]*cz;
            out[o2+0] = c[7]*ax + c[8]*bx + c[9]*cx;
            out[o2+1] = c[7]*ay + c[8]*by + c[9]*cy;
            out[o2+2] = c[7]*az + c[8]*bz + c[9]*cz;
            lam_ws[e] = c[6];
        }
    }
}

// ---------------------------------------------------------------------------
__global__ void zero_kernel(float* __restrict__ p, int n)
{
    int i = blockIdx.x * blockDim.x + threadIdx.x;
    if (i < n) p[i] = 0.0f;
}

__global__ void seg_sum_kernel(const int* __restrict__ idx, const int* __restrict__ edge_attr,
                               const int* __restrict__ node_type, const float* __restrict__ out,
                               float* __restrict__ sums, float* __restrict__ cnt)
{
    int e = blockIdx.x * blockDim.x + threadIdx.x;
    if (e >= NE) return;
    if (edge_attr[e] != -1) return;
    const int n = idx[e];
    if (node_type[2 * n + 1] != -1) return;
    atomicAdd(&cnt[n], 1.0f);
    #pragma unroll
    for (int tns = 0; tns < 3; ++tns)
        #pragma unroll
        for (int c2 = 0; c2 < 3; ++c2)
            atomicAdd(&sums[(size_t)tns * 3 * NN + (size_t)n * 3 + c2],
                      out[(size_t)tns * NE * 3 + (size_t)e * 3 + c2]);
}

__global__ void apply_mean_kernel(const int* __restrict__ idx, const int* __restrict__ edge_attr,
                                  const int* __restrict__ node_type, float* __restrict__ out,
                                  const float* __restrict__ sums, const float* __restrict__ cnt)
{
    int e = blockIdx.x * blockDim.x + threadIdx.x;
    if (e >= NE) return;
    if (edge_attr[e] != -1) return;
    const int n = idx[e];
    if (node_type[2 * n + 1] != -1) return;
    const float ic = 1.0f / fmaxf(cnt[n], 1.0f);
    #pragma unroll
    for (int tns = 0; tns < 3; ++tns)
        #pragma unroll
        for (int c2 = 0; c2 < 3; ++c2)
            out[(size_t)tns * NE * 3 + (size_t)e * 3 + c2] -=
                sums[(size_t)tns * 3 * NN + (size_t)n * 3 + c2] * ic;
}

__global__ void finalize_kernel(const int* __restrict__ senders, const int* __restrict__ receivers,
                                const float* __restrict__ sp, const float* __restrict__ rp,
                                const float* __restrict__ wn, const float* __restrict__ lam,
                                float* __restrict__ out)
{
    int e = blockIdx.x * blockDim.x + threadIdx.x;
    if (e >= NE) return;
    const int s = senders[e], r = receivers[e];
    const float wsv = wn[s], wrv = wn[r];
    const float inv = 1.0f / (wsv + wrv);
    const size_t b = (size_t)e * 3;
    const float spx = sp[b+0], spy = sp[b+1], spz = sp[b+2];
    const float rpx = rp[b+0], rpy = rp[b+1], rpz = rp[b+2];
    const float lx = rpx - (wsv * spx + wrv * rpx) * inv;
    const float ly = rpy - (wsv * spy + wrv * rpy) * inv;
    const float lz = rpz - (wsv * spz + wrv * rpz) * inv;
    const float lv = lam[e];
    const float gx = out[b+0] * lv, gy = out[b+1] * lv, gz = out[b+2] * lv;
    const size_t tb = (size_t)NE * 3 + b;
    const float tx = out[tb+0] - (ly * gz - lz * gy);
    const float ty = out[tb+1] - (lz * gx - lx * gz);
    const float tz = out[tb+2] - (lx * gy - ly * gx);
    out[tb+0] = tx; out[tb+1] = ty; out[tb+2] = tz;
}

// ---------------------------------------------------------------------------
extern "C" void kernel_launch(void* const* d_in, const int* in_sizes, int n_in,
                              void* d_out, int out_size, void* d_ws, size_t ws_size,
                              hipStream_t stream)
{
    (void)in_sizes; (void)n_in; (void)out_size; (void)ws_size;

    const int* edge_index    = (const int*)d_in[0];
    const int* edge_attr     = (const int*)d_in[1];
    const int* node_type     = (const int*)d_in[2];
    const float* senders_pos = (const float*)d_in[3];
    const float* recv_pos    = (const float*)d_in[4];
    const float* vector_a    = (const float*)d_in[5];
    const float* vector_b    = (const float*)d_in[6];
    const float* vector_c    = (const float*)d_in[7];
    const float* latent      = (const float*)d_in[8];
    const float* w_nodes     = (const float*)d_in[9];

    MlpArgs ma;
    const int douts[4] = {3, 3, 1, 3};
    const int obase[4] = {0, 3, 6, 7};
    for (int i = 0; i < 4; ++i) {
        ma.m[i].W1 = (const float*)d_in[10 + i * 4 + 0];
        ma.m[i].b1 = (const float*)d_in[10 + i * 4 + 1];
        ma.m[i].W2 = (const float*)d_in[10 + i * 4 + 2];
        ma.m[i].b2 = (const float*)d_in[10 + i * 4 + 3];
        ma.m[i].dout = douts[i];
        ma.m[i].obase = obase[i];
    }

    float* out = (float*)d_out;
    // ws (floats): [lambda NE][sIn 9N][cIn N][sOut 9N][cOut N][w1t 32768 f-equiv]
    float* lam    = (float*)d_ws;
    float* segbuf = lam + NE;
    float* sIn    = segbuf;
    float* cIn    = sIn + 9 * NN;
    float* sOut   = cIn + NN;
    float* cOut   = sOut + 9 * NN;
    unsigned short* w1t = (unsigned short*)(cOut + NN);

    const int* senders   = edge_index;
    const int* receivers = edge_index + NE;

    hipLaunchKernelGGL(prep_w1t_kernel, dim3((4 * DD * DD + 255) / 256), dim3(256), 0, stream,
                       ma.m[0].W1, ma.m[1].W1, ma.m[2].W1, ma.m[3].W1, w1t);
    hipLaunchKernelGGL(zero_kernel, dim3((20 * NN + 255) / 256), dim3(256), 0, stream,
                       segbuf, 20 * NN);
    hipLaunchKernelGGL(mlp_mfma_kernel, dim3((NE + 127) / 128), dim3(256), 0, stream,
                       latent, w1t, vector_a, vector_b, vector_c, out, lam, ma);
    dim3 gE((NE + 255) / 256);
    hipLaunchKernelGGL(seg_sum_kernel,    gE, dim3(256), 0, stream, receivers, edge_attr, node_type, out, sIn, cIn);
    hipLaunchKernelGGL(apply_mean_kernel, gE, dim3(256), 0, stream, receivers, edge_attr, node_type, out, sIn, cIn);
    hipLaunchKernelGGL(seg_sum_kernel,    gE, dim3(256), 0, stream, senders, edge_attr, node_type, out, sOut, cOut);
    hipLaunchKernelGGL(apply_mean_kernel, gE, dim3(256), 0, stream, senders, edge_attr, node_type, out, sOut, cOut);
    hipLaunchKernelGGL(finalize_kernel,   gE, dim3(256), 0, stream, senders, receivers, senders_pos, recv_pos, w_nodes, lam, out);
}